// Round 8
// baseline (277.545 us; speedup 1.0000x reference)
//
#include <hip/hip_runtime.h>
#include <hip/hip_cooperative_groups.h>

namespace cg = cooperative_groups;

// ReceptiveFieldNorm, N=16 C=3 H=W=768, fp32. Two iterations (win 51 then 13
// at 256x256). This revision: all five low-res stages merged into ONE
// cooperative kernel (256 blocks x 1024 threads = 1 block/CU co-resident,
// grid.sync between stages). 2 dispatches total.

#define N_B 16
#define CCH 3
#define HF 768
#define HL 256
#define SLICE (HL * HL)
#define TOT_L (N_B * SLICE)
#define EPSV 1e-3f

__device__ __forceinline__ int cnt(int i, int P) {
  int hi = i + P; if (hi > HL - 1) hi = HL - 1;
  int lo = i - P; if (lo < 0) lo = 0;
  return hi - lo + 1;
}

// Dual zero-padded horizontal box-sum; 4 independent rows (one per group g).
template <int P>
__device__ __forceinline__ void hbox2g(float a, float b, int g, int j,
    float (*s0)[HL], float (*s1)[HL], float (*wtA)[4], float (*wtB)[4],
    float& ra, float& rb) {
  int lane = j & 63, w = j >> 6;
  __syncthreads();  // protect LDS reuse across calls
#pragma unroll
  for (int d = 1; d < 64; d <<= 1) {
    float ta = __shfl_up(a, (unsigned)d);
    float tb = __shfl_up(b, (unsigned)d);
    if (lane >= d) { a += ta; b += tb; }
  }
  if (lane == 63) { wtA[g][w] = a; wtB[g][w] = b; }
  __syncthreads();
  float offa = 0.f, offb = 0.f;
  for (int ww = 0; ww < w; ++ww) { offa += wtA[g][ww]; offb += wtB[g][ww]; }
  s0[g][j] = a + offa;
  s1[g][j] = b + offb;
  __syncthreads();
  int hi = j + P; if (hi > HL - 1) hi = HL - 1;
  int lo = j - P - 1;
  ra = s0[g][hi]; rb = s1[g][hi];
  if (lo >= 0) { ra -= s0[g][lo]; rb -= s1[g][lo]; }
}

// ---------- stage 0 body: subsample + channel stats + h-scan(25) for one
// quad of 4 subsample rows (quad index b in [0,1024)).
__device__ __forceinline__ void sub_quad(int b, int tid,
    const float* __restrict__ x, float* __restrict__ u, float* __restrict__ v,
    float* __restrict__ t0, float* __restrict__ t1,
    float (*stagebuf)[HF], float (*s0)[HL], float (*s1)[HL],
    float (*wtA)[4], float (*wtB)[4]) {
  int n = b >> 6;           // 64 quads per image
  int ib = (b & 63) << 2;   // first of 4 subsample rows
  int g = tid >> 8, j = tid & 255;
  int srow = tid / 192, scol = (tid % 192) * 4;  // staging map (tid < 768)
  float ua = 0.f, va = 0.f;
  const size_t imgbase = (size_t)n * CCH * HF * HF;
  for (int c = 0; c < CCH; ++c) {
    __syncthreads();  // stage buffer reuse
    if (tid < 768) {
      const float* src = x + imgbase + (size_t)c * HF * HF
                       + (size_t)(3 * (ib + srow) + 1) * HF + scol;
      *(float4*)&stagebuf[srow][scol] = *(const float4*)src;
    }
    __syncthreads();
    float val = stagebuf[g][3 * j + 1];
    ua += val;
    va += val * val;
  }
  float uu = ua * (1.f / 3.f), vv = va * (1.f / 3.f);
  size_t base = ((size_t)(n * HL) + (ib + g)) * HL;
  u[base + j] = uu;
  v[base + j] = vv;
  float ra, rb;
  hbox2g<25>(uu, vv, g, j, s0, s1, wtA, wtB, ra, rb);
  t0[base + j] = ra;
  t1[base + j] = rb;
}

// ---------- vertical sliding-window box (radius P) + fused epilogue/h-scan(P2)
// group g handles rows seg*16 + g + 4t (t=0..3); window slides by 4.
// MODE 0: -> a=1/std, b=-mean/std; h-scan P2 -> out
// MODE 2: -> A,B maps (m0,m1); iter-2 stats from u,v; h-scan P2 -> out
// MODE 1: -> A,B maps only
template <int P, int MODE, int P2>
__device__ void vstage(int bid, int tid, const float* __restrict__ in0,
    const float* __restrict__ in1, float* __restrict__ out0,
    float* __restrict__ out1, const float* __restrict__ u,
    const float* __restrict__ v, float* __restrict__ m0,
    float* __restrict__ m1,
    float (*s0)[HL], float (*s1)[HL], float (*wtA)[4], float (*wtB)[4]) {
  int n = bid >> 4, seg = bid & 15;
  int g = tid >> 8, j = tid & 255;
  const float* p0 = in0 + (size_t)n * SLICE;
  const float* p1 = in1 + (size_t)n * SLICE;
  int i = seg * 16 + g;
  float a0 = 0.f, a1 = 0.f;
  {
    int lo = i - P; if (lo < 0) lo = 0;
    int hi = i + P; if (hi > HL - 1) hi = HL - 1;
    for (int r = lo; r <= hi; ++r) { a0 += p0[r * HL + j]; a1 += p1[r * HL + j]; }
  }
  float cj = (float)cnt(j, P);
#pragma unroll
  for (int t = 0; t < 4; ++t) {
    float invM = 1.f / (cj * (float)cnt(i, P));
    size_t idx = (size_t)n * SLICE + (size_t)i * HL + j;
    float o0 = 0.f, o1 = 0.f;
    if constexpr (MODE == 0) {
      float xm = a0 * invM, x2m = a1 * invM;
      float var = x2m - xm * xm; if (var < 0.f) var = 0.f;
      float inv = 1.f / sqrtf(var + EPSV);
      o0 = inv; o1 = -xm * inv;
    } else {
      float A = a0 * invM, B = a1 * invM;
      m0[idx] = A; m1[idx] = B;
      if constexpr (MODE == 2) {
        float un = u[idx], vn = v[idx];
        o0 = A * un + B;
        o1 = A * A * vn + 2.f * A * B * un + B * B;
      }
    }
    if constexpr (MODE != 1) {
      float ra, rb;
      hbox2g<P2>(o0, o1, g, j, s0, s1, wtA, wtB, ra, rb);
      out0[idx] = ra;
      out1[idx] = rb;
    }
    if (t < 3) {
#pragma unroll
      for (int d = 1; d <= 4; ++d) {
        int ar = i + P + d;
        if (ar <= HL - 1) { a0 += p0[ar * HL + j]; a1 += p1[ar * HL + j]; }
        int sr = i - P + d - 1;
        if (sr >= 0) { a0 -= p0[sr * HL + j]; a1 -= p1[sr * HL + j]; }
      }
      i += 4;
    }
  }
}

// ---------- the merged cooperative kernel: 256 blocks x 1024 threads
__global__ __launch_bounds__(1024) void k_coop(const float* __restrict__ x,
    float* __restrict__ u, float* __restrict__ v, float* __restrict__ t0,
    float* __restrict__ t1, float* __restrict__ t2, float* __restrict__ t3,
    float* __restrict__ A1, float* __restrict__ B1, float* __restrict__ A2,
    float* __restrict__ B2) {
  __shared__ float stagebuf[4][HF];
  __shared__ float s0[4][HL], s1[4][HL];
  __shared__ float wtA[4][4], wtB[4][4];
  cg::grid_group grid = cg::this_grid();
  int tid = threadIdx.x;
#pragma unroll
  for (int qb = 0; qb < 4; ++qb)
    sub_quad(blockIdx.x * 4 + qb, tid, x, u, v, t0, t1, stagebuf, s0, s1, wtA, wtB);
  grid.sync();
  vstage<25, 0, 25>(blockIdx.x, tid, t0, t1, t2, t3, nullptr, nullptr,
                    nullptr, nullptr, s0, s1, wtA, wtB);
  grid.sync();
  vstage<25, 2, 6>(blockIdx.x, tid, t2, t3, t0, t1, u, v, A1, B1,
                   s0, s1, wtA, wtB);
  grid.sync();
  vstage<6, 0, 6>(blockIdx.x, tid, t0, t1, t2, t3, nullptr, nullptr,
                  nullptr, nullptr, s0, s1, wtA, wtB);
  grid.sync();
  vstage<6, 1, 0>(blockIdx.x, tid, t2, t3, nullptr, nullptr, nullptr, nullptr,
                  A2, B2, s0, s1, wtA, wtB);
}

// ---------- bilinear upsample weights for 256 -> 768 (period-3 pattern)
__device__ __forceinline__ void upw(int q, int& i0, int& i1, float& w1) {
  int d = q / 3;
  int r = q - 3 * d;
  if (r == 1) { i0 = d; i1 = d; w1 = 0.f; }
  else if (r == 2) { i0 = d; i1 = d + 1; if (i1 > HL - 1) i1 = HL - 1; w1 = 1.f / 3.f; }
  else { i1 = d; i0 = d - 1; if (i0 < 0) i0 = 0; w1 = 2.f / 3.f; }
}

// ---------- fused output: out = A2up * (A1up * x + B1up) + B2up
__global__ __launch_bounds__(192) void k_final(
    const float* __restrict__ x, const float* __restrict__ A1m,
    const float* __restrict__ B1m, const float* __restrict__ A2m,
    const float* __restrict__ B2m, float* __restrict__ out) {
  __shared__ float ry[4][HL];
  int nb = blockIdx.x;  // n*768 + y
  int y = nb % HF;
  int n = nb / HF;
  int t = threadIdx.x;
  int iy0, iy1;
  float wy1;
  upw(y, iy0, iy1, wy1);
  float wy0 = 1.f - wy1;
  size_t mb = (size_t)n * SLICE;
  for (int col = t; col < HL; col += 192) {
    ry[0][col] = wy0 * A1m[mb + (size_t)iy0 * HL + col] + wy1 * A1m[mb + (size_t)iy1 * HL + col];
    ry[1][col] = wy0 * B1m[mb + (size_t)iy0 * HL + col] + wy1 * B1m[mb + (size_t)iy1 * HL + col];
    ry[2][col] = wy0 * A2m[mb + (size_t)iy0 * HL + col] + wy1 * A2m[mb + (size_t)iy1 * HL + col];
    ry[3][col] = wy0 * B2m[mb + (size_t)iy0 * HL + col] + wy1 * B2m[mb + (size_t)iy1 * HL + col];
  }
  __syncthreads();
  float A1c[4], B1c[4], A2c[4], B2c[4];
#pragma unroll
  for (int e = 0; e < 4; ++e) {
    int q = 4 * t + e;
    int ix0, ix1;
    float wx1;
    upw(q, ix0, ix1, wx1);
    float wx0 = 1.f - wx1;
    A1c[e] = wx0 * ry[0][ix0] + wx1 * ry[0][ix1];
    B1c[e] = wx0 * ry[1][ix0] + wx1 * ry[1][ix1];
    A2c[e] = wx0 * ry[2][ix0] + wx1 * ry[2][ix1];
    B2c[e] = wx0 * ry[3][ix0] + wx1 * ry[3][ix1];
  }
  size_t rowbase = ((size_t)(n * CCH) * HF + y) * HF + 4 * t;
#pragma unroll
  for (int c = 0; c < CCH; ++c) {
    const float4 xin = *(const float4*)(x + rowbase + (size_t)c * HF * HF);
    float4 o;
    o.x = A2c[0] * (A1c[0] * xin.x + B1c[0]) + B2c[0];
    o.y = A2c[1] * (A1c[1] * xin.y + B1c[1]) + B2c[1];
    o.z = A2c[2] * (A1c[2] * xin.z + B1c[2]) + B2c[2];
    o.w = A2c[3] * (A1c[3] * xin.w + B1c[3]) + B2c[3];
    *(float4*)(out + rowbase + (size_t)c * HF * HF) = o;
  }
}

extern "C" void kernel_launch(void* const* d_in, const int* in_sizes, int n_in,
                              void* d_out, int out_size, void* d_ws, size_t ws_size,
                              hipStream_t stream) {
  const float* x = (const float*)d_in[0];
  float* out = (float*)d_out;
  const size_t S = (size_t)TOT_L;
  float* wsf = (float*)d_ws;
  float *u, *v, *t0, *t1, *t2, *t3, *A1, *B1, *A2, *B2;
  if (ws_size >= 10 * S * sizeof(float)) {
    u = wsf;      v = u + S;   t0 = v + S;   t1 = t0 + S;  t2 = t1 + S;
    t3 = t2 + S;  A1 = t3 + S; B1 = A1 + S;  A2 = B1 + S;  B2 = A2 + S;
  } else {
    // Maps k_final reads stay in ws (16 MB); transients live at the head of
    // d_out (each fully written before read, every call).
    A1 = wsf; B1 = A1 + S; A2 = B1 + S; B2 = A2 + S;
    u = out; v = u + S; t0 = v + S; t1 = t0 + S; t2 = t1 + S; t3 = t2 + S;
  }

  const float* xa = x;
  void* args[] = {(void*)&xa, (void*)&u, (void*)&v, (void*)&t0, (void*)&t1,
                  (void*)&t2, (void*)&t3, (void*)&A1, (void*)&B1, (void*)&A2,
                  (void*)&B2};
  hipLaunchCooperativeKernel((const void*)k_coop, dim3(N_B * 16), dim3(1024),
                             args, 0, stream);
  k_final<<<N_B * HF, 192, 0, stream>>>(x, A1, B1, A2, B2, out);
}

// Round 9
// 159.857 us; speedup vs baseline: 1.7362x; 1.7362x over previous
//
#include <hip/hip_runtime.h>

// ReceptiveFieldNorm, N=16 C=3 H=W=768, fp32. Two iterations (win 51 then 13
// at 256x256). 4 dispatches: k1 (subsample+stats+H25), k_s12 (V25->f->V25
// in-register ->H25 -> A1,B1 + iter2 stats ->H6), k_s34 (V6->f6->V6->H6 ->
// A2,B2), k_final (fused upsample+affine). Box H/V commute is used to fuse
// each h-scan with the following v-box without materializing intermediates.

#define N_B 16
#define CCH 3
#define HF 768
#define HL 256
#define SLICE (HL * HL)
#define TOT_L (N_B * SLICE)
#define EPSV 1e-3f

__device__ __forceinline__ int cnt(int i, int P) {
  int hi = i + P; if (hi > HL - 1) hi = HL - 1;
  int lo = i - P; if (lo < 0) lo = 0;
  return hi - lo + 1;
}

// Dual zero-padded horizontal box-sum; 4 independent rows (one per group g).
template <int P>
__device__ __forceinline__ void hbox2g(float a, float b, int g, int j,
    float (*s0)[HL], float (*s1)[HL], float (*wtA)[4], float (*wtB)[4],
    float& ra, float& rb) {
  int lane = j & 63, w = j >> 6;
  __syncthreads();  // protect LDS reuse across calls
#pragma unroll
  for (int d = 1; d < 64; d <<= 1) {
    float ta = __shfl_up(a, (unsigned)d);
    float tb = __shfl_up(b, (unsigned)d);
    if (lane >= d) { a += ta; b += tb; }
  }
  if (lane == 63) { wtA[g][w] = a; wtB[g][w] = b; }
  __syncthreads();
  float offa = 0.f, offb = 0.f;
  for (int ww = 0; ww < w; ++ww) { offa += wtA[g][ww]; offb += wtB[g][ww]; }
  s0[g][j] = a + offa;
  s1[g][j] = b + offb;
  __syncthreads();
  int hi = j + P; if (hi > HL - 1) hi = HL - 1;
  int lo = j - P - 1;
  ra = s0[g][hi]; rb = s1[g][hi];
  if (lo >= 0) { ra -= s0[g][lo]; rb -= s1[g][lo]; }
}

// ---------- k1: subsample + channel stats + h-scan(P=25); stores raw u,v.
__global__ __launch_bounds__(1024) void k1(const float* __restrict__ x,
    float* __restrict__ u, float* __restrict__ v,
    float* __restrict__ t0, float* __restrict__ t1) {
  __shared__ float stage[4][HF];
  __shared__ float s0[4][HL], s1[4][HL];
  __shared__ float wtA[4][4], wtB[4][4];
  int b = blockIdx.x;
  int n = b >> 6;           // 64 blocks per image
  int ib = (b & 63) << 2;   // first of 4 subsample rows
  int tid = threadIdx.x;
  int g = tid >> 8, j = tid & 255;
  int srow = tid / 192, scol = (tid % 192) * 4;  // staging map (tid < 768)
  float ua = 0.f, va = 0.f;
  const size_t imgbase = (size_t)n * CCH * HF * HF;
  for (int c = 0; c < CCH; ++c) {
    __syncthreads();  // stage buffer reuse
    if (tid < 768) {
      const float* src = x + imgbase + (size_t)c * HF * HF
                       + (size_t)(3 * (ib + srow) + 1) * HF + scol;
      *(float4*)&stage[srow][scol] = *(const float4*)src;
    }
    __syncthreads();
    float val = stage[g][3 * j + 1];
    ua += val;
    va += val * val;
  }
  float uu = ua * (1.f / 3.f), vv = va * (1.f / 3.f);
  size_t base = ((size_t)(n * HL) + (ib + g)) * HL;
  u[base + j] = uu;
  v[base + j] = vv;
  float ra, rb;
  hbox2g<25>(uu, vv, g, j, s0, s1, wtA, wtB, ra, rb);
  t0[base + j] = ra;
  t1[base + j] = rb;
}

// ---------- fused cascade kernel template parts
// Production rows rp = r0 - P + 4t + g (t = 0..NSTEP-1). Thread (g,j) keeps a
// sliding T-window (vertical box radius P over T rows of column j) producing
// f(...) = (a,b) at rp, stages the 4 rows/step in LDS, and every thread
// accumulates staged rows into the second vertical box sums of its 4 owned
// rows (r0 + g + 4q). Zero-padding: out-of-range rows contribute nothing.

// ---------- k_s12: T0,T1,u,v -> A1,B1 (maps) and Tp0,Tp1 = H6(u2,v2)
__global__ __launch_bounds__(1024) void k_s12(const float* __restrict__ T0,
    const float* __restrict__ T1, const float* __restrict__ u,
    const float* __restrict__ v, float* __restrict__ A1,
    float* __restrict__ B1, float* __restrict__ Tp0, float* __restrict__ Tp1) {
  __shared__ float stg[2][4][HL];
  __shared__ float s0[4][HL], s1[4][HL];
  __shared__ float wtA[4][4], wtB[4][4];
  const int P = 25;
  int n = blockIdx.x >> 4, seg = blockIdx.x & 15;
  int tid = threadIdx.x, g = tid >> 8, j = tid & 255;
  int r0 = seg * 16;
  const float* p0 = T0 + (size_t)n * SLICE;
  const float* p1 = T1 + (size_t)n * SLICE;
  float sa[4] = {0.f, 0.f, 0.f, 0.f}, sb[4] = {0.f, 0.f, 0.f, 0.f};
  float w0 = 0.f, w1 = 0.f;
  {
    int rp0 = r0 - P + g;
    int lo = rp0 - P; if (lo < 0) lo = 0;
    int hi = rp0 + P; if (hi > HL - 1) hi = HL - 1;
    for (int r = lo; r <= hi; ++r) { w0 += p0[r * HL + j]; w1 += p1[r * HL + j]; }
  }
  float cj = (float)cnt(j, P);
  for (int t = 0; t < 17; ++t) {
    int rp = r0 - P + 4 * t + g;
    float av = 0.f, bv = 0.f;
    if (rp >= 0 && rp < HL) {
      float invM = 1.f / (cj * (float)cnt(rp, P));
      float xm = w0 * invM, x2m = w1 * invM;
      float var = x2m - xm * xm; if (var < 0.f) var = 0.f;
      float inv = 1.f / sqrtf(var + EPSV);
      av = inv; bv = -xm * inv;
    }
    __syncthreads();  // protect stg reads of previous step
    stg[0][g][j] = av; stg[1][g][j] = bv;
    __syncthreads();
#pragma unroll
    for (int gg = 0; gg < 4; ++gg) {
      int rs = r0 - P + 4 * t + gg;
      if (rs < 0 || rs >= HL) continue;
      float aa = stg[0][gg][j], bb = stg[1][gg][j];
#pragma unroll
      for (int q = 0; q < 4; ++q) {
        int d = rs - (r0 + g + 4 * q);
        if (d >= -P && d <= P) { sa[q] += aa; sb[q] += bb; }
      }
    }
    if (t < 16) {
#pragma unroll
      for (int dd = 1; dd <= 4; ++dd) {
        int ar = rp + P + dd;
        if (ar >= 0 && ar < HL) { w0 += p0[ar * HL + j]; w1 += p1[ar * HL + j]; }
        int sr = rp - P + dd - 1;
        if (sr >= 0 && sr < HL) { w0 -= p0[sr * HL + j]; w1 -= p1[sr * HL + j]; }
      }
    }
  }
  size_t nb = (size_t)n * SLICE;
  float u2q[4], v2q[4];
#pragma unroll
  for (int q = 0; q < 4; ++q) {
    int i = r0 + g + 4 * q;
    float ra, rb;
    hbox2g<25>(sa[q], sb[q], g, j, s0, s1, wtA, wtB, ra, rb);
    float invM = 1.f / (cj * (float)cnt(i, 25));
    float Av = ra * invM, Bv = rb * invM;
    size_t idx = nb + (size_t)i * HL + j;
    A1[idx] = Av; B1[idx] = Bv;
    float un = u[idx], vn = v[idx];
    u2q[q] = Av * un + Bv;
    v2q[q] = Av * Av * vn + 2.f * Av * Bv * un + Bv * Bv;
  }
#pragma unroll
  for (int q = 0; q < 4; ++q) {
    int i = r0 + g + 4 * q;
    float ra, rb;
    hbox2g<6>(u2q[q], v2q[q], g, j, s0, s1, wtA, wtB, ra, rb);
    size_t idx = nb + (size_t)i * HL + j;
    Tp0[idx] = ra; Tp1[idx] = rb;
  }
}

// ---------- k_s34: Tp0,Tp1 -> A2,B2 (maps)
__global__ __launch_bounds__(1024) void k_s34(const float* __restrict__ Tp0,
    const float* __restrict__ Tp1, float* __restrict__ A2,
    float* __restrict__ B2) {
  __shared__ float stg[2][4][HL];
  __shared__ float s0[4][HL], s1[4][HL];
  __shared__ float wtA[4][4], wtB[4][4];
  const int P = 6;
  int n = blockIdx.x >> 4, seg = blockIdx.x & 15;
  int tid = threadIdx.x, g = tid >> 8, j = tid & 255;
  int r0 = seg * 16;
  const float* p0 = Tp0 + (size_t)n * SLICE;
  const float* p1 = Tp1 + (size_t)n * SLICE;
  float sa[4] = {0.f, 0.f, 0.f, 0.f}, sb[4] = {0.f, 0.f, 0.f, 0.f};
  float w0 = 0.f, w1 = 0.f;
  {
    int rp0 = r0 - P + g;
    int lo = rp0 - P; if (lo < 0) lo = 0;
    int hi = rp0 + P; if (hi > HL - 1) hi = HL - 1;
    for (int r = lo; r <= hi; ++r) { w0 += p0[r * HL + j]; w1 += p1[r * HL + j]; }
  }
  float cj = (float)cnt(j, P);
  for (int t = 0; t < 7; ++t) {
    int rp = r0 - P + 4 * t + g;
    float av = 0.f, bv = 0.f;
    if (rp >= 0 && rp < HL) {
      float invM = 1.f / (cj * (float)cnt(rp, P));
      float xm = w0 * invM, x2m = w1 * invM;
      float var = x2m - xm * xm; if (var < 0.f) var = 0.f;
      float inv = 1.f / sqrtf(var + EPSV);
      av = inv; bv = -xm * inv;
    }
    __syncthreads();
    stg[0][g][j] = av; stg[1][g][j] = bv;
    __syncthreads();
#pragma unroll
    for (int gg = 0; gg < 4; ++gg) {
      int rs = r0 - P + 4 * t + gg;
      if (rs < 0 || rs >= HL) continue;
      float aa = stg[0][gg][j], bb = stg[1][gg][j];
#pragma unroll
      for (int q = 0; q < 4; ++q) {
        int d = rs - (r0 + g + 4 * q);
        if (d >= -P && d <= P) { sa[q] += aa; sb[q] += bb; }
      }
    }
    if (t < 6) {
#pragma unroll
      for (int dd = 1; dd <= 4; ++dd) {
        int ar = rp + P + dd;
        if (ar >= 0 && ar < HL) { w0 += p0[ar * HL + j]; w1 += p1[ar * HL + j]; }
        int sr = rp - P + dd - 1;
        if (sr >= 0 && sr < HL) { w0 -= p0[sr * HL + j]; w1 -= p1[sr * HL + j]; }
      }
    }
  }
  size_t nb = (size_t)n * SLICE;
#pragma unroll
  for (int q = 0; q < 4; ++q) {
    int i = r0 + g + 4 * q;
    float ra, rb;
    hbox2g<6>(sa[q], sb[q], g, j, s0, s1, wtA, wtB, ra, rb);
    float invM = 1.f / (cj * (float)cnt(i, 6));
    size_t idx = nb + (size_t)i * HL + j;
    A2[idx] = ra * invM;
    B2[idx] = rb * invM;
  }
}

// ---------- bilinear upsample weights for 256 -> 768 (period-3 pattern)
__device__ __forceinline__ void upw(int q, int& i0, int& i1, float& w1) {
  int d = q / 3;
  int r = q - 3 * d;
  if (r == 1) { i0 = d; i1 = d; w1 = 0.f; }
  else if (r == 2) { i0 = d; i1 = d + 1; if (i1 > HL - 1) i1 = HL - 1; w1 = 1.f / 3.f; }
  else { i1 = d; i0 = d - 1; if (i0 < 0) i0 = 0; w1 = 2.f / 3.f; }
}

// ---------- fused output: out = A2up * (A1up * x + B1up) + B2up
__global__ __launch_bounds__(192) void k_final(
    const float* __restrict__ x, const float* __restrict__ A1m,
    const float* __restrict__ B1m, const float* __restrict__ A2m,
    const float* __restrict__ B2m, float* __restrict__ out) {
  __shared__ float ry[4][HL];
  int nb = blockIdx.x;  // n*768 + y
  int y = nb % HF;
  int n = nb / HF;
  int t = threadIdx.x;
  int iy0, iy1;
  float wy1;
  upw(y, iy0, iy1, wy1);
  float wy0 = 1.f - wy1;
  size_t mb = (size_t)n * SLICE;
  for (int col = t; col < HL; col += 192) {
    ry[0][col] = wy0 * A1m[mb + (size_t)iy0 * HL + col] + wy1 * A1m[mb + (size_t)iy1 * HL + col];
    ry[1][col] = wy0 * B1m[mb + (size_t)iy0 * HL + col] + wy1 * B1m[mb + (size_t)iy1 * HL + col];
    ry[2][col] = wy0 * A2m[mb + (size_t)iy0 * HL + col] + wy1 * A2m[mb + (size_t)iy1 * HL + col];
    ry[3][col] = wy0 * B2m[mb + (size_t)iy0 * HL + col] + wy1 * B2m[mb + (size_t)iy1 * HL + col];
  }
  __syncthreads();
  float A1c[4], B1c[4], A2c[4], B2c[4];
#pragma unroll
  for (int e = 0; e < 4; ++e) {
    int q = 4 * t + e;
    int ix0, ix1;
    float wx1;
    upw(q, ix0, ix1, wx1);
    float wx0 = 1.f - wx1;
    A1c[e] = wx0 * ry[0][ix0] + wx1 * ry[0][ix1];
    B1c[e] = wx0 * ry[1][ix0] + wx1 * ry[1][ix1];
    A2c[e] = wx0 * ry[2][ix0] + wx1 * ry[2][ix1];
    B2c[e] = wx0 * ry[3][ix0] + wx1 * ry[3][ix1];
  }
  size_t rowbase = ((size_t)(n * CCH) * HF + y) * HF + 4 * t;
#pragma unroll
  for (int c = 0; c < CCH; ++c) {
    const float4 xin = *(const float4*)(x + rowbase + (size_t)c * HF * HF);
    float4 o;
    o.x = A2c[0] * (A1c[0] * xin.x + B1c[0]) + B2c[0];
    o.y = A2c[1] * (A1c[1] * xin.y + B1c[1]) + B2c[1];
    o.z = A2c[2] * (A1c[2] * xin.z + B1c[2]) + B2c[2];
    o.w = A2c[3] * (A1c[3] * xin.w + B1c[3]) + B2c[3];
    *(float4*)(out + rowbase + (size_t)c * HF * HF) = o;
  }
}

extern "C" void kernel_launch(void* const* d_in, const int* in_sizes, int n_in,
                              void* d_out, int out_size, void* d_ws, size_t ws_size,
                              hipStream_t stream) {
  const float* x = (const float*)d_in[0];
  float* out = (float*)d_out;
  const size_t S = (size_t)TOT_L;
  float* wsf = (float*)d_ws;
  float *u, *v, *t0, *t1, *t2, *t3, *A1, *B1, *A2, *B2;
  if (ws_size >= 10 * S * sizeof(float)) {
    u = wsf;      v = u + S;   t0 = v + S;   t1 = t0 + S;  t2 = t1 + S;
    t3 = t2 + S;  A1 = t3 + S; B1 = A1 + S;  A2 = B1 + S;  B2 = A2 + S;
  } else {
    // Maps k_final reads stay in ws (16 MB); transients live at the head of
    // d_out (each fully written before read, every call).
    A1 = wsf; B1 = A1 + S; A2 = B1 + S; B2 = A2 + S;
    u = out; v = u + S; t0 = v + S; t1 = t0 + S; t2 = t1 + S; t3 = t2 + S;
  }

  k1<<<N_B * 64, 1024, 0, stream>>>(x, u, v, t0, t1);
  k_s12<<<N_B * 16, 1024, 0, stream>>>(t0, t1, u, v, A1, B1, t2, t3);
  k_s34<<<N_B * 16, 1024, 0, stream>>>(t2, t3, A2, B2);
  k_final<<<N_B * HF, 192, 0, stream>>>(x, A1, B1, A2, B2, out);
}

// Round 10
// 105.150 us; speedup vs baseline: 2.6395x; 1.5203x over previous
//
#include <hip/hip_runtime.h>

// ReceptiveFieldNorm, N=16 C=3 H=W=768, fp32. Two iterations (win 51 then 13
// at 256x256). All vertical boxes are horizontal shfl-scans in transposed
// orientation (LDS-exchange transposed writes). 5 dispatches:
//   k1: subsample+stats -> u,v [N]; H25-scan -> S [T]
//   k2: [T] scan25 (=V25) -> f -> scan25 (=V25 of a,b) -> P [N]
//   k3: [N] scan25 (=H25) -> A1,B1; iter2 stats u2,v2; H6-scan -> Q [T]
//   k4: [T] scan6 (=V6) -> f6 -> scan6 -> R [N]
//   k_final: H6-scan of R rows iy0/iy1 (A2,B2) + upsample + fused affine out

#define N_B 16
#define CCH 3
#define HF 768
#define HL 256
#define SLICE (HL * HL)
#define TOT_L (N_B * SLICE)
#define EPSV 1e-3f

__device__ __forceinline__ int cnt(int i, int P) {
  int hi = i + P; if (hi > HL - 1) hi = HL - 1;
  int lo = i - P; if (lo < 0) lo = 0;
  return hi - lo + 1;
}

// Dual zero-padded horizontal box-sum of a 256-wide row per group g.
// 3 syncthreads. Works for any number of active groups (block >= 256*G thr).
template <int P, int G>
__device__ __forceinline__ void hbox2g(float a, float b, int g, int j,
    float (*s0)[HL], float (*s1)[HL], float (*wtA)[4], float (*wtB)[4],
    float& ra, float& rb) {
  int lane = j & 63, w = j >> 6;
  __syncthreads();  // protect LDS reuse across calls
#pragma unroll
  for (int d = 1; d < 64; d <<= 1) {
    float ta = __shfl_up(a, (unsigned)d);
    float tb = __shfl_up(b, (unsigned)d);
    if (lane >= d) { a += ta; b += tb; }
  }
  if (lane == 63) { wtA[g][w] = a; wtB[g][w] = b; }
  __syncthreads();
  float offa = 0.f, offb = 0.f;
  for (int ww = 0; ww < w; ++ww) { offa += wtA[g][ww]; offb += wtB[g][ww]; }
  s0[g][j] = a + offa;
  s1[g][j] = b + offb;
  __syncthreads();
  int hi = j + P; if (hi > HL - 1) hi = HL - 1;
  int lo = j - P - 1;
  ra = s0[g][hi]; rb = s1[g][hi];
  if (lo >= 0) { ra -= s0[g][lo]; rb -= s1[g][lo]; }
}

// Exchange the 4 per-group register values through LDS and write them as a
// transposed float4 per column: dst[jj*HL + col0 .. col0+3].
__device__ __forceinline__ void xpose_write4(float ra, float rb, int g, int j,
    int tid, float (*s0)[HL], float (*s1)[HL],
    float* __restrict__ d0, float* __restrict__ d1, size_t nb, int col0) {
  __syncthreads();
  s0[g][j] = ra; s1[g][j] = rb;
  __syncthreads();
  if (tid < HL) {
    float4 va, vb;
    va.x = s0[0][tid]; va.y = s0[1][tid]; va.z = s0[2][tid]; va.w = s0[3][tid];
    vb.x = s1[0][tid]; vb.y = s1[1][tid]; vb.z = s1[2][tid]; vb.w = s1[3][tid];
    *(float4*)(d0 + nb + (size_t)tid * HL + col0) = va;
    *(float4*)(d1 + nb + (size_t)tid * HL + col0) = vb;
  }
}

// ---------- k1: subsample + channel stats -> u,v [N]; H25 scan -> S [T]
__global__ __launch_bounds__(1024) void k1(const float* __restrict__ x,
    float* __restrict__ u, float* __restrict__ v,
    float* __restrict__ S0, float* __restrict__ S1) {
  __shared__ float stage[4][HF];
  __shared__ float s0[4][HL], s1[4][HL];
  __shared__ float wtA[4][4], wtB[4][4];
  int b = blockIdx.x;
  int n = b >> 6;           // 64 blocks per image
  int ib = (b & 63) << 2;   // first of 4 subsample rows
  int tid = threadIdx.x;
  int g = tid >> 8, j = tid & 255;
  int srow = tid / 192, scol = (tid % 192) * 4;  // staging map (tid < 768)
  float ua = 0.f, va = 0.f;
  const size_t imgbase = (size_t)n * CCH * HF * HF;
  for (int c = 0; c < CCH; ++c) {
    __syncthreads();  // stage buffer reuse
    if (tid < 768) {
      const float* src = x + imgbase + (size_t)c * HF * HF
                       + (size_t)(3 * (ib + srow) + 1) * HF + scol;
      *(float4*)&stage[srow][scol] = *(const float4*)src;
    }
    __syncthreads();
    float val = stage[g][3 * j + 1];
    ua += val;
    va += val * val;
  }
  float uu = ua * (1.f / 3.f), vv = va * (1.f / 3.f);
  size_t nb = (size_t)n * SLICE;
  size_t base = nb + (size_t)(ib + g) * HL;
  u[base + j] = uu;
  v[base + j] = vv;
  float ra, rb;
  hbox2g<25, 4>(uu, vv, g, j, s0, s1, wtA, wtB, ra, rb);
  // S[T]: S[col=j][row=ib+g]
  xpose_write4(ra, rb, g, j, tid, s0, s1, S0, S1, nb, ib);
}

// ---------- k2: [T] scan25 -> box(u,v) -> f=(a,b) -> scan25 -> P [N]
__global__ __launch_bounds__(1024) void k2(const float* __restrict__ S0,
    const float* __restrict__ S1, float* __restrict__ P0,
    float* __restrict__ P1) {
  __shared__ float s0[4][HL], s1[4][HL];
  __shared__ float wtA[4][4], wtB[4][4];
  int n = blockIdx.x >> 6, strip = blockIdx.x & 63;
  int tid = threadIdx.x, g = tid >> 8, j = tid & 255;
  int c = strip * 4 + g;  // image col (T-row)
  size_t nb = (size_t)n * SLICE;
  float sa = S0[nb + (size_t)c * HL + j];
  float sb = S1[nb + (size_t)c * HL + j];
  float bu, bv;
  hbox2g<25, 4>(sa, sb, g, j, s0, s1, wtA, wtB, bu, bv);  // full box at (j,c)
  float invM = 1.f / ((float)cnt(j, 25) * (float)cnt(c, 25));
  float xm = bu * invM, x2m = bv * invM;
  float var = x2m - xm * xm; if (var < 0.f) var = 0.f;
  float inv = 1.f / sqrtf(var + EPSV);
  float av = inv, bv2 = -xm * inv;
  float ra, rb;
  hbox2g<25, 4>(av, bv2, g, j, s0, s1, wtA, wtB, ra, rb);  // V25(a,b)
  // P[N]: P[row=j][col=c]
  xpose_write4(ra, rb, g, j, tid, s0, s1, P0, P1, nb, strip * 4);
}

// ---------- k3: [N] scan25 -> A1,B1; iter2 stats; H6 scan -> Q [T]
__global__ __launch_bounds__(1024) void k3(const float* __restrict__ P0,
    const float* __restrict__ P1, const float* __restrict__ u,
    const float* __restrict__ v, float* __restrict__ A1,
    float* __restrict__ B1, float* __restrict__ Q0, float* __restrict__ Q1) {
  __shared__ float s0[4][HL], s1[4][HL];
  __shared__ float wtA[4][4], wtB[4][4];
  int n = blockIdx.x >> 6, strip = blockIdx.x & 63;
  int tid = threadIdx.x, g = tid >> 8, j = tid & 255;
  int i = strip * 4 + g;  // image row
  size_t nb = (size_t)n * SLICE;
  size_t idx = nb + (size_t)i * HL + j;
  float pa = P0[idx], pb = P1[idx];
  float ba, bb;
  hbox2g<25, 4>(pa, pb, g, j, s0, s1, wtA, wtB, ba, bb);  // box(a), box(b)
  float invM = 1.f / ((float)cnt(i, 25) * (float)cnt(j, 25));
  float Av = ba * invM, Bv = bb * invM;
  A1[idx] = Av;
  B1[idx] = Bv;
  float un = u[idx], vn = v[idx];
  float u2 = Av * un + Bv;
  float v2 = Av * Av * vn + 2.f * Av * Bv * un + Bv * Bv;
  float ra, rb;
  hbox2g<6, 4>(u2, v2, g, j, s0, s1, wtA, wtB, ra, rb);  // H6(u2,v2)
  // Q[T]: Q[col=j][row=i]
  xpose_write4(ra, rb, g, j, tid, s0, s1, Q0, Q1, nb, strip * 4);
}

// ---------- k4: [T] scan6 -> box6(u2,v2) -> f6 -> scan6 -> R [N]
__global__ __launch_bounds__(1024) void k4(const float* __restrict__ Q0,
    const float* __restrict__ Q1, float* __restrict__ R0,
    float* __restrict__ R1) {
  __shared__ float s0[4][HL], s1[4][HL];
  __shared__ float wtA[4][4], wtB[4][4];
  int n = blockIdx.x >> 6, strip = blockIdx.x & 63;
  int tid = threadIdx.x, g = tid >> 8, j = tid & 255;
  int c = strip * 4 + g;  // image col
  size_t nb = (size_t)n * SLICE;
  float qa = Q0[nb + (size_t)c * HL + j];
  float qb = Q1[nb + (size_t)c * HL + j];
  float bu, bv;
  hbox2g<6, 4>(qa, qb, g, j, s0, s1, wtA, wtB, bu, bv);  // full box6 at (j,c)
  float invM = 1.f / ((float)cnt(j, 6) * (float)cnt(c, 6));
  float xm = bu * invM, x2m = bv * invM;
  float var = x2m - xm * xm; if (var < 0.f) var = 0.f;
  float inv = 1.f / sqrtf(var + EPSV);
  float av = inv, bv2 = -xm * inv;
  float ra, rb;
  hbox2g<6, 4>(av, bv2, g, j, s0, s1, wtA, wtB, ra, rb);  // V6(a2,b2)
  // R[N]: R[row=j][col=c]
  xpose_write4(ra, rb, g, j, tid, s0, s1, R0, R1, nb, strip * 4);
}

// ---------- bilinear upsample weights for 256 -> 768 (period-3 pattern)
__device__ __forceinline__ void upw(int q, int& i0, int& i1, float& w1) {
  int d = q / 3;
  int r = q - 3 * d;
  if (r == 1) { i0 = d; i1 = d; w1 = 0.f; }
  else if (r == 2) { i0 = d; i1 = d + 1; if (i1 > HL - 1) i1 = HL - 1; w1 = 1.f / 3.f; }
  else { i1 = d; i0 = d - 1; if (i0 < 0) i0 = 0; w1 = 2.f / 3.f; }
}

// ---------- fused output: H6-scan of R rows (A2,B2) + upsample + affine
__global__ __launch_bounds__(256) void k_final(
    const float* __restrict__ x, const float* __restrict__ A1m,
    const float* __restrict__ B1m, const float* __restrict__ R0,
    const float* __restrict__ R1, float* __restrict__ out) {
  __shared__ float ry[4][HL];
  __shared__ float s0[1][HL], s1[1][HL];
  __shared__ float wtA[1][4], wtB[1][4];
  int nb_ = blockIdx.x;  // n*768 + y
  int y = nb_ % HF;
  int n = nb_ / HF;
  int t = threadIdx.x;  // 0..255
  int iy0, iy1;
  float wy1;
  upw(y, iy0, iy1, wy1);
  float wy0 = 1.f - wy1;
  size_t mb = (size_t)n * SLICE;
  // maps 0,1: bilinear-y of A1,B1
  ry[0][t] = wy0 * A1m[mb + (size_t)iy0 * HL + t] + wy1 * A1m[mb + (size_t)iy1 * HL + t];
  ry[1][t] = wy0 * B1m[mb + (size_t)iy0 * HL + t] + wy1 * B1m[mb + (size_t)iy1 * HL + t];
  // maps 2,3: H6-scan R rows iy0/iy1 -> A2,B2 rows, then bilinear-y
  float cj6 = (float)cnt(t, 6);
  float ra, rb;
  hbox2g<6, 1>(R0[mb + (size_t)iy0 * HL + t], R1[mb + (size_t)iy0 * HL + t],
               0, t, s0, s1, wtA, wtB, ra, rb);
  float inv0 = 1.f / ((float)cnt(iy0, 6) * cj6);
  float A20 = ra * inv0, B20 = rb * inv0;
  hbox2g<6, 1>(R0[mb + (size_t)iy1 * HL + t], R1[mb + (size_t)iy1 * HL + t],
               0, t, s0, s1, wtA, wtB, ra, rb);
  float inv1 = 1.f / ((float)cnt(iy1, 6) * cj6);
  ry[2][t] = wy0 * A20 + wy1 * (ra * inv1);
  ry[3][t] = wy0 * B20 + wy1 * (rb * inv1);
  __syncthreads();
  if (t < 192) {
    float A1c[4], B1c[4], A2c[4], B2c[4];
#pragma unroll
    for (int e = 0; e < 4; ++e) {
      int q = 4 * t + e;
      int ix0, ix1;
      float wx1;
      upw(q, ix0, ix1, wx1);
      float wx0 = 1.f - wx1;
      A1c[e] = wx0 * ry[0][ix0] + wx1 * ry[0][ix1];
      B1c[e] = wx0 * ry[1][ix0] + wx1 * ry[1][ix1];
      A2c[e] = wx0 * ry[2][ix0] + wx1 * ry[2][ix1];
      B2c[e] = wx0 * ry[3][ix0] + wx1 * ry[3][ix1];
    }
    size_t rowbase = ((size_t)(n * CCH) * HF + y) * HF + 4 * t;
#pragma unroll
    for (int c = 0; c < CCH; ++c) {
      const float4 xin = *(const float4*)(x + rowbase + (size_t)c * HF * HF);
      float4 o;
      o.x = A2c[0] * (A1c[0] * xin.x + B1c[0]) + B2c[0];
      o.y = A2c[1] * (A1c[1] * xin.y + B1c[1]) + B2c[1];
      o.z = A2c[2] * (A1c[2] * xin.z + B1c[2]) + B2c[2];
      o.w = A2c[3] * (A1c[3] * xin.w + B1c[3]) + B2c[3];
      *(float4*)(out + rowbase + (size_t)c * HF * HF) = o;
    }
  }
}

extern "C" void kernel_launch(void* const* d_in, const int* in_sizes, int n_in,
                              void* d_out, int out_size, void* d_ws, size_t ws_size,
                              hipStream_t stream) {
  const float* x = (const float*)d_in[0];
  float* out = (float*)d_out;
  const size_t S = (size_t)TOT_L;
  float* wsf = (float*)d_ws;
  float *u, *v, *S0, *S1, *P0, *P1, *A1, *B1, *R0, *R1, *Q0, *Q1;
  if (ws_size >= 10 * S * sizeof(float)) {
    u = wsf;      v = u + S;   S0 = v + S;   S1 = S0 + S;  P0 = S1 + S;
    P1 = P0 + S;  A1 = P1 + S; B1 = A1 + S;  R0 = B1 + S;  R1 = R0 + S;
  } else {
    // Buffers k_final reads stay in ws (16 MB); transients live at the head
    // of d_out (each fully written before read, every call).
    A1 = wsf; B1 = A1 + S; R0 = B1 + S; R1 = R0 + S;
    u = out; v = u + S; S0 = v + S; S1 = S0 + S; P0 = S1 + S; P1 = P0 + S;
  }
  Q0 = S0; Q1 = S1;  // S dead after k2; k3 writes Q there, k4 reads

  k1<<<N_B * 64, 1024, 0, stream>>>(x, u, v, S0, S1);
  k2<<<N_B * 64, 1024, 0, stream>>>(S0, S1, P0, P1);
  k3<<<N_B * 64, 1024, 0, stream>>>(P0, P1, u, v, A1, B1, Q0, Q1);
  k4<<<N_B * 64, 1024, 0, stream>>>(Q0, Q1, R0, R1);
  k_final<<<N_B * HF, 256, 0, stream>>>(x, A1, B1, R0, R1, out);
}

// Round 11
// 99.114 us; speedup vs baseline: 2.8003x; 1.0609x over previous
//
#include <hip/hip_runtime.h>

// ReceptiveFieldNorm, N=16 C=3 H=W=768, fp32. Two iterations (win 51 then 13
// at 256x256). All vertical boxes are horizontal shfl-scans in transposed
// orientation. 5 dispatches (provably minimal: 4 orientation flips).
// This revision: float2-packed intermediates + direct transposed reads from
// the scan LDS (fewer barriers, halved VMEM instruction count).

#define N_B 16
#define CCH 3
#define HF 768
#define HL 256
#define SLICE (HL * HL)
#define TOT_L (N_B * SLICE)
#define EPSV 1e-3f

__device__ __forceinline__ int cnt(int i, int P) {
  int hi = i + P; if (hi > HL - 1) hi = HL - 1;
  int lo = i - P; if (lo < 0) lo = 0;
  return hi - lo + 1;
}

// Dual inclusive prefix scan of a 256-wide row per group g into s[g][*].
// 3 syncthreads (incl. entry guard protecting previous LDS consumers).
__device__ __forceinline__ void scan2g(float a, float b, int g, int j,
    float2 (*s)[HL], float2 (*wt)[4]) {
  int lane = j & 63, w = j >> 6;
  __syncthreads();  // guard: all consumers of s/wt from prior use are done
#pragma unroll
  for (int d = 1; d < 64; d <<= 1) {
    float ta = __shfl_up(a, (unsigned)d);
    float tb = __shfl_up(b, (unsigned)d);
    if (lane >= d) { a += ta; b += tb; }
  }
  if (lane == 63) wt[g][w] = make_float2(a, b);
  __syncthreads();
  float offa = 0.f, offb = 0.f;
  for (int ww = 0; ww < w; ++ww) { float2 t = wt[g][ww]; offa += t.x; offb += t.y; }
  s[g][j] = make_float2(a + offa, b + offb);
  __syncthreads();
}

// Zero-padded box result at position j from prefix array s[g].
template <int P>
__device__ __forceinline__ float2 boxr(const float2 (*s)[HL], int g, int j) {
  int hi = j + P; if (hi > HL - 1) hi = HL - 1;
  int lo = j - P - 1;
  float2 r = s[g][hi];
  if (lo >= 0) { float2 l = s[g][lo]; r.x -= l.x; r.y -= l.y; }
  return r;
}

// Transposed float2x4 write: thread tid (<256) writes dst[tid][col0..col0+3].
template <int P>
__device__ __forceinline__ void xpose_store(const float2 (*s)[HL], int tid,
    float2* __restrict__ dst, size_t nb, int col0) {
  if (tid < HL) {
    float2 r0 = boxr<P>(s, 0, tid);
    float2 r1 = boxr<P>(s, 1, tid);
    float2 r2 = boxr<P>(s, 2, tid);
    float2 r3 = boxr<P>(s, 3, tid);
    float4* d = (float4*)(dst + nb + (size_t)tid * HL + col0);
    d[0] = make_float4(r0.x, r0.y, r1.x, r1.y);
    d[1] = make_float4(r2.x, r2.y, r3.x, r3.y);
  }
}

// ---------- k1: subsample + channel stats -> UV [N]; H25 scan -> S [T]
__global__ __launch_bounds__(1024) void k1(const float* __restrict__ x,
    float2* __restrict__ UV, float2* __restrict__ Spk) {
  __shared__ float stage[4][HF];
  __shared__ float2 s[4][HL];
  __shared__ float2 wt[4][4];
  int b = blockIdx.x;
  int n = b >> 6;           // 64 blocks per image
  int ib = (b & 63) << 2;   // first of 4 subsample rows
  int tid = threadIdx.x;
  int g = tid >> 8, j = tid & 255;
  int srow = tid / 192, scol = (tid % 192) * 4;  // staging map (tid < 768)
  float ua = 0.f, va = 0.f;
  const size_t imgbase = (size_t)n * CCH * HF * HF;
  for (int c = 0; c < CCH; ++c) {
    __syncthreads();  // stage buffer reuse
    if (tid < 768) {
      const float* src = x + imgbase + (size_t)c * HF * HF
                       + (size_t)(3 * (ib + srow) + 1) * HF + scol;
      *(float4*)&stage[srow][scol] = *(const float4*)src;
    }
    __syncthreads();
    float val = stage[g][3 * j + 1];
    ua += val;
    va += val * val;
  }
  float uu = ua * (1.f / 3.f), vv = va * (1.f / 3.f);
  size_t nb = (size_t)n * SLICE;
  UV[nb + (size_t)(ib + g) * HL + j] = make_float2(uu, vv);
  scan2g(uu, vv, g, j, s, wt);
  xpose_store<25>(s, tid, Spk, nb, ib);  // S[col=j][row=ib+g]
}

// ---------- k2: [T] scan25 -> box(u,v) -> f -> scan25 -> P [N]
__global__ __launch_bounds__(1024) void k2(const float2* __restrict__ Spk,
    float2* __restrict__ Ppk) {
  __shared__ float2 s[4][HL];
  __shared__ float2 wt[4][4];
  int n = blockIdx.x >> 6, strip = blockIdx.x & 63;
  int tid = threadIdx.x, g = tid >> 8, j = tid & 255;
  int c = strip * 4 + g;  // image col (T-row)
  size_t nb = (size_t)n * SLICE;
  float2 sv = Spk[nb + (size_t)c * HL + j];
  scan2g(sv.x, sv.y, g, j, s, wt);        // V25 prefix
  float2 bu = boxr<25>(s, g, j);          // full box25 at (row j, col c)
  float invM = 1.f / ((float)cnt(j, 25) * (float)cnt(c, 25));
  float xm = bu.x * invM, x2m = bu.y * invM;
  float var = x2m - xm * xm; if (var < 0.f) var = 0.f;
  float inv = 1.f / sqrtf(var + EPSV);
  scan2g(inv, -xm * inv, g, j, s, wt);    // V25 prefix of (a,b)
  xpose_store<25>(s, tid, Ppk, nb, strip * 4);  // P[row=j][col=c]
}

// ---------- k3: [N] scan25 -> A1,B1; iter2 stats; H6 scan -> Q [T]
__global__ __launch_bounds__(1024) void k3(const float2* __restrict__ Ppk,
    const float2* __restrict__ UV, float2* __restrict__ AB1,
    float2* __restrict__ Qpk) {
  __shared__ float2 s[4][HL];
  __shared__ float2 wt[4][4];
  int n = blockIdx.x >> 6, strip = blockIdx.x & 63;
  int tid = threadIdx.x, g = tid >> 8, j = tid & 255;
  int i = strip * 4 + g;  // image row
  size_t nb = (size_t)n * SLICE;
  size_t idx = nb + (size_t)i * HL + j;
  float2 pv = Ppk[idx];
  scan2g(pv.x, pv.y, g, j, s, wt);        // H25 prefix of (a,b)
  float2 bb = boxr<25>(s, g, j);
  float invM = 1.f / ((float)cnt(i, 25) * (float)cnt(j, 25));
  float Av = bb.x * invM, Bv = bb.y * invM;
  AB1[idx] = make_float2(Av, Bv);
  float2 uv = UV[idx];
  float u2 = Av * uv.x + Bv;
  float v2 = Av * Av * uv.y + 2.f * Av * Bv * uv.x + Bv * Bv;
  scan2g(u2, v2, g, j, s, wt);            // H6 prefix of (u2,v2)
  xpose_store<6>(s, tid, Qpk, nb, strip * 4);  // Q[col=j][row=i]
}

// ---------- k4: [T] scan6 -> box6 -> f6 -> scan6 -> R [N]
__global__ __launch_bounds__(1024) void k4(const float2* __restrict__ Qpk,
    float2* __restrict__ Rpk) {
  __shared__ float2 s[4][HL];
  __shared__ float2 wt[4][4];
  int n = blockIdx.x >> 6, strip = blockIdx.x & 63;
  int tid = threadIdx.x, g = tid >> 8, j = tid & 255;
  int c = strip * 4 + g;  // image col
  size_t nb = (size_t)n * SLICE;
  float2 qv = Qpk[nb + (size_t)c * HL + j];
  scan2g(qv.x, qv.y, g, j, s, wt);        // V6 prefix
  float2 bu = boxr<6>(s, g, j);           // full box6 at (row j, col c)
  float invM = 1.f / ((float)cnt(j, 6) * (float)cnt(c, 6));
  float xm = bu.x * invM, x2m = bu.y * invM;
  float var = x2m - xm * xm; if (var < 0.f) var = 0.f;
  float inv = 1.f / sqrtf(var + EPSV);
  scan2g(inv, -xm * inv, g, j, s, wt);    // V6 prefix of (a2,b2)
  xpose_store<6>(s, tid, Rpk, nb, strip * 4);  // R[row=j][col=c]
}

// ---------- bilinear upsample weights for 256 -> 768 (period-3 pattern)
__device__ __forceinline__ void upw(int q, int& i0, int& i1, float& w1) {
  int d = q / 3;
  int r = q - 3 * d;
  if (r == 1) { i0 = d; i1 = d; w1 = 0.f; }
  else if (r == 2) { i0 = d; i1 = d + 1; if (i1 > HL - 1) i1 = HL - 1; w1 = 1.f / 3.f; }
  else { i1 = d; i0 = d - 1; if (i0 < 0) i0 = 0; w1 = 2.f / 3.f; }
}

// ---------- fused output: H6-scan of R rows (A2,B2) + upsample + affine
__global__ __launch_bounds__(256) void k_final(
    const float* __restrict__ x, const float2* __restrict__ AB1,
    const float2* __restrict__ Rpk, float* __restrict__ out) {
  __shared__ float2 ry01[HL], ry23[HL];
  __shared__ float2 s[1][HL];
  __shared__ float2 wt[1][4];
  int nb_ = blockIdx.x;  // n*768 + y
  int y = nb_ % HF;
  int n = nb_ / HF;
  int t = threadIdx.x;  // 0..255
  int iy0, iy1;
  float wy1;
  upw(y, iy0, iy1, wy1);
  float wy0 = 1.f - wy1;
  size_t mb = (size_t)n * SLICE;
  // maps 0,1: bilinear-y of A1,B1
  float2 a0 = AB1[mb + (size_t)iy0 * HL + t];
  float2 a1 = AB1[mb + (size_t)iy1 * HL + t];
  ry01[t] = make_float2(wy0 * a0.x + wy1 * a1.x, wy0 * a0.y + wy1 * a1.y);
  // maps 2,3: H6-scan R rows iy0/iy1 -> A2,B2 rows, then bilinear-y
  float cj6 = (float)cnt(t, 6);
  float2 r0v = Rpk[mb + (size_t)iy0 * HL + t];
  scan2g(r0v.x, r0v.y, 0, t, s, wt);
  float2 b0 = boxr<6>(s, 0, t);
  float inv0 = 1.f / ((float)cnt(iy0, 6) * cj6);
  float A20 = b0.x * inv0, B20 = b0.y * inv0;
  float2 r1v = Rpk[mb + (size_t)iy1 * HL + t];
  scan2g(r1v.x, r1v.y, 0, t, s, wt);
  float2 b1 = boxr<6>(s, 0, t);
  float inv1 = 1.f / ((float)cnt(iy1, 6) * cj6);
  ry23[t] = make_float2(wy0 * A20 + wy1 * b1.x * inv1,
                        wy0 * B20 + wy1 * b1.y * inv1);
  __syncthreads();
  if (t < 192) {
    float A1c[4], B1c[4], A2c[4], B2c[4];
#pragma unroll
    for (int e = 0; e < 4; ++e) {
      int q = 4 * t + e;
      int ix0, ix1;
      float wx1;
      upw(q, ix0, ix1, wx1);
      float wx0 = 1.f - wx1;
      float2 m0 = ry01[ix0], m1 = ry01[ix1];
      float2 m2 = ry23[ix0], m3 = ry23[ix1];
      A1c[e] = wx0 * m0.x + wx1 * m1.x;
      B1c[e] = wx0 * m0.y + wx1 * m1.y;
      A2c[e] = wx0 * m2.x + wx1 * m3.x;
      B2c[e] = wx0 * m2.y + wx1 * m3.y;
    }
    size_t rowbase = ((size_t)(n * CCH) * HF + y) * HF + 4 * t;
#pragma unroll
    for (int c = 0; c < CCH; ++c) {
      const float4 xin = *(const float4*)(x + rowbase + (size_t)c * HF * HF);
      float4 o;
      o.x = A2c[0] * (A1c[0] * xin.x + B1c[0]) + B2c[0];
      o.y = A2c[1] * (A1c[1] * xin.y + B1c[1]) + B2c[1];
      o.z = A2c[2] * (A1c[2] * xin.z + B1c[2]) + B2c[2];
      o.w = A2c[3] * (A1c[3] * xin.w + B1c[3]) + B2c[3];
      *(float4*)(out + rowbase + (size_t)c * HF * HF) = o;
    }
  }
}

extern "C" void kernel_launch(void* const* d_in, const int* in_sizes, int n_in,
                              void* d_out, int out_size, void* d_ws, size_t ws_size,
                              hipStream_t stream) {
  const float* x = (const float*)d_in[0];
  float* out = (float*)d_out;
  const size_t S = (size_t)TOT_L;  // elements per packed (float2) array
  float2 *UV, *Spk, *Ppk, *AB1, *Rpk, *Qpk;
  if (ws_size >= 10 * S * sizeof(float)) {
    float2* w = (float2*)d_ws;
    UV = w; Spk = UV + S; Ppk = Spk + S; AB1 = Ppk + S; Rpk = AB1 + S;
  } else {
    // Buffers k_final reads stay in ws (16 MB); transients live at the head
    // of d_out (each fully written before read, every call).
    AB1 = (float2*)d_ws; Rpk = AB1 + S;
    UV = (float2*)out; Spk = UV + S; Ppk = Spk + S;
  }
  Qpk = Spk;  // S dead after k2; k3 writes Q there, k4 reads

  k1<<<N_B * 64, 1024, 0, stream>>>(x, UV, Spk);
  k2<<<N_B * 64, 1024, 0, stream>>>(Spk, Ppk);
  k3<<<N_B * 64, 1024, 0, stream>>>(Ppk, UV, AB1, Qpk);
  k4<<<N_B * 64, 1024, 0, stream>>>(Qpk, Rpk);
  k_final<<<N_B * HF, 256, 0, stream>>>(x, AB1, Rpk, out);
}

// Round 12
// 96.205 us; speedup vs baseline: 2.8849x; 1.0302x over previous
//
#include <hip/hip_runtime.h>

// ReceptiveFieldNorm, N=16 C=3 H=W=768, fp32. Two iterations (win 51 then 13
// at 256x256). All vertical boxes are horizontal shfl-scans in transposed
// orientation. 5 dispatches (minimal: 4 orientation flips). This revision:
// direct strided loads in k1 (no staging), 2-barrier double-buffered scans,
// wy1==0 fast path in k_final.

#define N_B 16
#define CCH 3
#define HF 768
#define HL 256
#define SLICE (HL * HL)
#define TOT_L (N_B * SLICE)
#define EPSV 1e-3f

__device__ __forceinline__ int cnt(int i, int P) {
  int hi = i + P; if (hi > HL - 1) hi = HL - 1;
  int lo = i - P; if (lo < 0) lo = 0;
  return hi - lo + 1;
}

// Dual inclusive prefix scan of a 256-wide row per group g into s[g][*].
// 2 syncthreads. Caller must pass a FRESH buffer pair (s,wt) per call
// (double-buffer) -- there is no entry guard.
__device__ __forceinline__ void scan2g(float a, float b, int g, int j,
    float2 (*s)[HL], float2 (*wt)[4]) {
  int lane = j & 63, w = j >> 6;
#pragma unroll
  for (int d = 1; d < 64; d <<= 1) {
    float ta = __shfl_up(a, (unsigned)d);
    float tb = __shfl_up(b, (unsigned)d);
    if (lane >= d) { a += ta; b += tb; }
  }
  if (lane == 63) wt[g][w] = make_float2(a, b);
  __syncthreads();
  float offa = 0.f, offb = 0.f;
  for (int ww = 0; ww < w; ++ww) { float2 t = wt[g][ww]; offa += t.x; offb += t.y; }
  s[g][j] = make_float2(a + offa, b + offb);
  __syncthreads();
}

// Zero-padded box result at position j from prefix array s[g].
template <int P>
__device__ __forceinline__ float2 boxr(const float2 (*s)[HL], int g, int j) {
  int hi = j + P; if (hi > HL - 1) hi = HL - 1;
  int lo = j - P - 1;
  float2 r = s[g][hi];
  if (lo >= 0) { float2 l = s[g][lo]; r.x -= l.x; r.y -= l.y; }
  return r;
}

// Transposed float2x4 write: thread tid (<256) writes dst[tid][col0..col0+3].
template <int P>
__device__ __forceinline__ void xpose_store(const float2 (*s)[HL], int tid,
    float2* __restrict__ dst, size_t nb, int col0) {
  if (tid < HL) {
    float2 r0 = boxr<P>(s, 0, tid);
    float2 r1 = boxr<P>(s, 1, tid);
    float2 r2 = boxr<P>(s, 2, tid);
    float2 r3 = boxr<P>(s, 3, tid);
    float4* d = (float4*)(dst + nb + (size_t)tid * HL + col0);
    d[0] = make_float4(r0.x, r0.y, r1.x, r1.y);
    d[1] = make_float4(r2.x, r2.y, r3.x, r3.y);
  }
}

// ---------- k1: subsample + channel stats -> UV [N]; H25 scan -> S [T]
__global__ __launch_bounds__(1024) void k1(const float* __restrict__ x,
    float2* __restrict__ UV, float2* __restrict__ Spk) {
  __shared__ float2 sA[4][HL];
  __shared__ float2 wtA[4][4];
  int b = blockIdx.x;
  int n = b >> 6;           // 64 blocks per image
  int ib = (b & 63) << 2;   // first of 4 subsample rows
  int tid = threadIdx.x;
  int g = tid >> 8, j = tid & 255;
  const float* xp = x + (size_t)n * CCH * HF * HF
                  + (size_t)(3 * (ib + g) + 1) * HF + (3 * j + 1);
  float c0 = xp[0], c1 = xp[HF * HF], c2 = xp[2 * HF * HF];
  float uu = (c0 + c1 + c2) * (1.f / 3.f);
  float vv = (c0 * c0 + c1 * c1 + c2 * c2) * (1.f / 3.f);
  size_t nb = (size_t)n * SLICE;
  UV[nb + (size_t)(ib + g) * HL + j] = make_float2(uu, vv);
  scan2g(uu, vv, g, j, sA, wtA);
  xpose_store<25>(sA, tid, Spk, nb, ib);  // S[col=j][row=ib+g]
}

// ---------- k2: [T] scan25 -> box(u,v) -> f -> scan25 -> P [N]
__global__ __launch_bounds__(1024) void k2(const float2* __restrict__ Spk,
    float2* __restrict__ Ppk) {
  __shared__ float2 sA[4][HL], sB[4][HL];
  __shared__ float2 wtA[4][4], wtB[4][4];
  int n = blockIdx.x >> 6, strip = blockIdx.x & 63;
  int tid = threadIdx.x, g = tid >> 8, j = tid & 255;
  int c = strip * 4 + g;  // image col (T-row)
  size_t nb = (size_t)n * SLICE;
  float2 sv = Spk[nb + (size_t)c * HL + j];
  scan2g(sv.x, sv.y, g, j, sA, wtA);      // V25 prefix
  float2 bu = boxr<25>(sA, g, j);         // full box25 at (row j, col c)
  float invM = 1.f / ((float)cnt(j, 25) * (float)cnt(c, 25));
  float xm = bu.x * invM, x2m = bu.y * invM;
  float var = x2m - xm * xm; if (var < 0.f) var = 0.f;
  float inv = 1.f / sqrtf(var + EPSV);
  scan2g(inv, -xm * inv, g, j, sB, wtB);  // V25 prefix of (a,b)
  xpose_store<25>(sB, tid, Ppk, nb, strip * 4);  // P[row=j][col=c]
}

// ---------- k3: [N] scan25 -> A1,B1; iter2 stats; H6 scan -> Q [T]
__global__ __launch_bounds__(1024) void k3(const float2* __restrict__ Ppk,
    const float2* __restrict__ UV, float2* __restrict__ AB1,
    float2* __restrict__ Qpk) {
  __shared__ float2 sA[4][HL], sB[4][HL];
  __shared__ float2 wtA[4][4], wtB[4][4];
  int n = blockIdx.x >> 6, strip = blockIdx.x & 63;
  int tid = threadIdx.x, g = tid >> 8, j = tid & 255;
  int i = strip * 4 + g;  // image row
  size_t nb = (size_t)n * SLICE;
  size_t idx = nb + (size_t)i * HL + j;
  float2 pv = Ppk[idx];
  scan2g(pv.x, pv.y, g, j, sA, wtA);      // H25 prefix of (a,b)
  float2 bb = boxr<25>(sA, g, j);
  float invM = 1.f / ((float)cnt(i, 25) * (float)cnt(j, 25));
  float Av = bb.x * invM, Bv = bb.y * invM;
  AB1[idx] = make_float2(Av, Bv);
  float2 uv = UV[idx];
  float u2 = Av * uv.x + Bv;
  float v2 = Av * Av * uv.y + 2.f * Av * Bv * uv.x + Bv * Bv;
  scan2g(u2, v2, g, j, sB, wtB);          // H6 prefix of (u2,v2)
  xpose_store<6>(sB, tid, Qpk, nb, strip * 4);  // Q[col=j][row=i]
}

// ---------- k4: [T] scan6 -> box6 -> f6 -> scan6 -> R [N]
__global__ __launch_bounds__(1024) void k4(const float2* __restrict__ Qpk,
    float2* __restrict__ Rpk) {
  __shared__ float2 sA[4][HL], sB[4][HL];
  __shared__ float2 wtA[4][4], wtB[4][4];
  int n = blockIdx.x >> 6, strip = blockIdx.x & 63;
  int tid = threadIdx.x, g = tid >> 8, j = tid & 255;
  int c = strip * 4 + g;  // image col
  size_t nb = (size_t)n * SLICE;
  float2 qv = Qpk[nb + (size_t)c * HL + j];
  scan2g(qv.x, qv.y, g, j, sA, wtA);      // V6 prefix
  float2 bu = boxr<6>(sA, g, j);          // full box6 at (row j, col c)
  float invM = 1.f / ((float)cnt(j, 6) * (float)cnt(c, 6));
  float xm = bu.x * invM, x2m = bu.y * invM;
  float var = x2m - xm * xm; if (var < 0.f) var = 0.f;
  float inv = 1.f / sqrtf(var + EPSV);
  scan2g(inv, -xm * inv, g, j, sB, wtB);  // V6 prefix of (a2,b2)
  xpose_store<6>(sB, tid, Rpk, nb, strip * 4);  // R[row=j][col=c]
}

// ---------- bilinear upsample weights for 256 -> 768 (period-3 pattern)
__device__ __forceinline__ void upw(int q, int& i0, int& i1, float& w1) {
  int d = q / 3;
  int r = q - 3 * d;
  if (r == 1) { i0 = d; i1 = d; w1 = 0.f; }
  else if (r == 2) { i0 = d; i1 = d + 1; if (i1 > HL - 1) i1 = HL - 1; w1 = 1.f / 3.f; }
  else { i1 = d; i0 = d - 1; if (i0 < 0) i0 = 0; w1 = 2.f / 3.f; }
}

// ---------- fused output: H6-scan of R rows (A2,B2) + upsample + affine
__global__ __launch_bounds__(256) void k_final(
    const float* __restrict__ x, const float2* __restrict__ AB1,
    const float2* __restrict__ Rpk, float* __restrict__ out) {
  __shared__ float2 ry01[HL], ry23[HL];
  __shared__ float2 sA[1][HL], sB[1][HL];
  __shared__ float2 wtA[1][4], wtB[1][4];
  int nb_ = blockIdx.x;  // n*768 + y
  int y = nb_ % HF;
  int n = nb_ / HF;
  int t = threadIdx.x;  // 0..255
  int iy0, iy1;
  float wy1;
  upw(y, iy0, iy1, wy1);
  float wy0 = 1.f - wy1;
  size_t mb = (size_t)n * SLICE;
  // maps 0,1: bilinear-y of A1,B1
  float2 a0 = AB1[mb + (size_t)iy0 * HL + t];
  float2 a1 = AB1[mb + (size_t)iy1 * HL + t];
  ry01[t] = make_float2(wy0 * a0.x + wy1 * a1.x, wy0 * a0.y + wy1 * a1.y);
  // maps 2,3: H6-scan R rows iy0/iy1 -> A2,B2 rows, then bilinear-y
  float cj6 = (float)cnt(t, 6);
  float2 r0v = Rpk[mb + (size_t)iy0 * HL + t];
  scan2g(r0v.x, r0v.y, 0, t, sA, wtA);
  float2 b0 = boxr<6>(sA, 0, t);
  float inv0 = 1.f / ((float)cnt(iy0, 6) * cj6);
  float A20 = b0.x * inv0, B20 = b0.y * inv0;
  if (wy1 == 0.f) {  // exact-sample rows (y%3==1): single map row suffices
    ry23[t] = make_float2(A20, B20);
  } else {
    float2 r1v = Rpk[mb + (size_t)iy1 * HL + t];
    scan2g(r1v.x, r1v.y, 0, t, sB, wtB);
    float2 b1 = boxr<6>(sB, 0, t);
    float inv1 = 1.f / ((float)cnt(iy1, 6) * cj6);
    ry23[t] = make_float2(wy0 * A20 + wy1 * b1.x * inv1,
                          wy0 * B20 + wy1 * b1.y * inv1);
  }
  __syncthreads();
  if (t < 192) {
    float A1c[4], B1c[4], A2c[4], B2c[4];
#pragma unroll
    for (int e = 0; e < 4; ++e) {
      int q = 4 * t + e;
      int ix0, ix1;
      float wx1;
      upw(q, ix0, ix1, wx1);
      float wx0 = 1.f - wx1;
      float2 m0 = ry01[ix0], m1 = ry01[ix1];
      float2 m2 = ry23[ix0], m3 = ry23[ix1];
      A1c[e] = wx0 * m0.x + wx1 * m1.x;
      B1c[e] = wx0 * m0.y + wx1 * m1.y;
      A2c[e] = wx0 * m2.x + wx1 * m3.x;
      B2c[e] = wx0 * m2.y + wx1 * m3.y;
    }
    size_t rowbase = ((size_t)(n * CCH) * HF + y) * HF + 4 * t;
#pragma unroll
    for (int c = 0; c < CCH; ++c) {
      const float4 xin = *(const float4*)(x + rowbase + (size_t)c * HF * HF);
      float4 o;
      o.x = A2c[0] * (A1c[0] * xin.x + B1c[0]) + B2c[0];
      o.y = A2c[1] * (A1c[1] * xin.y + B1c[1]) + B2c[1];
      o.z = A2c[2] * (A1c[2] * xin.z + B1c[2]) + B2c[2];
      o.w = A2c[3] * (A1c[3] * xin.w + B1c[3]) + B2c[3];
      *(float4*)(out + rowbase + (size_t)c * HF * HF) = o;
    }
  }
}

extern "C" void kernel_launch(void* const* d_in, const int* in_sizes, int n_in,
                              void* d_out, int out_size, void* d_ws, size_t ws_size,
                              hipStream_t stream) {
  const float* x = (const float*)d_in[0];
  float* out = (float*)d_out;
  const size_t S = (size_t)TOT_L;  // elements per packed (float2) array
  float2 *UV, *Spk, *Ppk, *AB1, *Rpk, *Qpk;
  if (ws_size >= 10 * S * sizeof(float)) {
    float2* w = (float2*)d_ws;
    UV = w; Spk = UV + S; Ppk = Spk + S; AB1 = Ppk + S; Rpk = AB1 + S;
  } else {
    // Buffers k_final reads stay in ws (16 MB); transients live at the head
    // of d_out (each fully written before read, every call).
    AB1 = (float2*)d_ws; Rpk = AB1 + S;
    UV = (float2*)out; Spk = UV + S; Ppk = Spk + S;
  }
  Qpk = Spk;  // S dead after k2; k3 writes Q there, k4 reads

  k1<<<N_B * 64, 1024, 0, stream>>>(x, UV, Spk);
  k2<<<N_B * 64, 1024, 0, stream>>>(Spk, Ppk);
  k3<<<N_B * 64, 1024, 0, stream>>>(Ppk, UV, AB1, Qpk);
  k4<<<N_B * 64, 1024, 0, stream>>>(Qpk, Rpk);
  k_final<<<N_B * HF, 256, 0, stream>>>(x, AB1, Rpk, out);
}